// Round 9
// baseline (661.850 us; speedup 1.0000x reference)
//
#include <hip/hip_runtime.h>
#include <hip/hip_bf16.h>

#define NHEAD 4
#define NXCD 8
#define EPT 8  // edges per thread in the edge kernel

typedef __hip_bfloat16 bf16;
typedef __hip_bfloat162 bf162;
typedef float f32x4 __attribute__((ext_vector_type(4)));  // native vec, NT-able

// ---------------------------------------------------------------------------
// Kernel 1: fused QKV projection + denom8 zeroing.
// q,k bf16 HEAD-MAJOR [4][N][16] (per-head 1.6MB slice; phase working set
// 3.2MB fits per-XCD 4MB L2 -- proven R7: FETCH dropped to 82MB).
// v fp32 direct to out in [N, d, h]. denom8 = 8 per-XCD copies, zeroed here.
// ---------------------------------------------------------------------------
__global__ __launch_bounds__(256) void qkv_kernel(
    const float* __restrict__ x,
    const float* __restrict__ Wq, const float* __restrict__ bq,
    const float* __restrict__ Wk, const float* __restrict__ bk,
    const float* __restrict__ Wv, const float* __restrict__ bv,
    bf16* __restrict__ qout, bf16* __restrict__ kout,
    float* __restrict__ vout, float* __restrict__ denom8, int n_nodes) {
  const size_t gtid = (size_t)blockIdx.x * 256 + threadIdx.x;
  const size_t nthreads = (size_t)gridDim.x * 256;
  const size_t dz = (size_t)n_nodes * NHEAD * NXCD;
  for (size_t idx = gtid; idx < dz; idx += nthreads) denom8[idx] = 0.f;

  __shared__ float xs[16][64];
  const int t = threadIdx.x;
  const int base = blockIdx.x * 16;
#pragma unroll
  for (int j = 0; j < 4; ++j) {
    const int idx = t + 256 * j;
    const int nn = idx >> 6, cc = idx & 63;
    xs[nn][cc] = (base + nn < n_nodes)
                     ? __builtin_nontemporal_load(&x[(size_t)(base + nn) * 64 + cc])
                     : 0.f;
  }
  __syncthreads();
  const int c = t & 63;
  const int qg = t >> 6;  // wave id

  float aq[4], ak[4], av[4];
  const float bqv = bq[c], bkv = bk[c], bvv = bv[c];
#pragma unroll
  for (int j = 0; j < 4; ++j) { aq[j] = bqv; ak[j] = bkv; av[j] = bvv; }

#pragma unroll 4
  for (int r = 0; r < 64; ++r) {
    const float wq = Wq[r * 64 + c];
    const float wk = Wk[r * 64 + c];
    const float wv = Wv[r * 64 + c];
#pragma unroll
    for (int j = 0; j < 4; ++j) {
      const float xv = xs[qg * 4 + j][r];  // wave-uniform addr -> LDS broadcast
      aq[j] = fmaf(xv, wq, aq[j]);
      ak[j] = fmaf(xv, wk, ak[j]);
      av[j] = fmaf(xv, wv, av[j]);
    }
  }
  const int h = c >> 4, d = c & 15;
#pragma unroll
  for (int j = 0; j < 4; ++j) {
    const int node = base + qg * 4 + j;
    if (node < n_nodes) {
      qout[((size_t)h * n_nodes + node) * 16 + d] = __float2bfloat16(aq[j]);
      kout[((size_t)h * n_nodes + node) * 16 + d] = __float2bfloat16(ak[j]);
      vout[(size_t)node * 64 + d * 4 + h] = av[j];
    }
  }
}

// ---------------------------------------------------------------------------
// Kernel 2: edge dots + XCD-LOCAL denominator atomics.
// Thread i owns edges {i + j*Q}; head-phased gathers (h outermost) over the
// L2-resident 3.2MB per-head slice; 782 blocks all co-resident.
// Atomics: workgroup-scope fetch_add into THIS XCD's denom copy (XCD id via
// s_getreg hwreg(HW_REG_XCC_ID)) -> executes in local XCD L2, no fabric
// transaction per touch (the 1.85e10 lines/s wall measured R3..R7).
// End-of-kernel writeback publishes the dirty L2 lines to the next dispatch.
// ---------------------------------------------------------------------------
__device__ __forceinline__ float dot8(uint4 a, uint4 b) {
  const unsigned* pa = &a.x;
  const unsigned* pb = &b.x;
  float acc = 0.f;
#pragma unroll
  for (int i = 0; i < 4; ++i) {
    const float2 fa = __bfloat1622float2(*(const bf162*)&pa[i]);
    const float2 fb = __bfloat1622float2(*(const bf162*)&pb[i]);
    acc = fmaf(fa.x, fb.x, acc);
    acc = fmaf(fa.y, fb.y, acc);
  }
  return acc;
}

__global__ __launch_bounds__(256, 4) void edge_kernel(
    const int* __restrict__ edge0, const int* __restrict__ edge1,
    const uint4* __restrict__ q, const uint4* __restrict__ k,
    f32x4* __restrict__ prods4, float* __restrict__ denom8,
    int n_edges, int n_nodes, int Q) {
  int xcd;
  asm volatile("s_getreg_b32 %0, hwreg(HW_REG_XCC_ID)" : "=s"(xcd));
  float* __restrict__ denomX = denom8 + (size_t)(xcd & 7) * n_nodes * NHEAD;

  const int i = blockIdx.x * 256 + threadIdx.x;

  int src[EPT], dst[EPT];
  float p[EPT][4];

#pragma unroll
  for (int j = 0; j < EPT; ++j) {
    const int e = i + j * Q;
    const bool ok = (i < Q) && (e < n_edges);
    src[j] = ok ? __builtin_nontemporal_load(&edge0[e]) : 0;
    dst[j] = ok ? __builtin_nontemporal_load(&edge1[e]) : 0;
  }

  // Head-phased gather + dot (per phase: 3.2MB slice shared by all blocks).
#pragma unroll
  for (int h = 0; h < 4; ++h) {
    const size_t hb = (size_t)h * n_nodes * 2;  // uint4 units
#pragma unroll
    for (int j = 0; j < EPT; ++j) {
      const size_t qb = hb + (size_t)src[j] * 2;
      const size_t kb = hb + (size_t)dst[j] * 2;
      const uint4 a0 = q[qb], a1 = q[qb + 1];
      const uint4 b0 = k[kb], b1 = k[kb + 1];
      p[j][h] = (dot8(a0, b0) + dot8(a1, b1)) * 0.25f;  // 1/sqrt(16)
    }
  }

#pragma unroll
  for (int j = 0; j < EPT; ++j) {
    const int e = i + j * Q;
    if ((i < Q) && (e < n_edges)) {
      const f32x4 pv = {p[j][0], p[j][1], p[j][2], p[j][3]};
      __builtin_nontemporal_store(pv, &prods4[e]);  // full-line NT, write-once
#pragma unroll
      for (int h = 0; h < 4; ++h) {
        __hip_atomic_fetch_add(&denomX[(size_t)src[j] * 4 + h], __expf(p[j][h]),
                               __ATOMIC_RELAXED, __HIP_MEMORY_SCOPE_WORKGROUP);
      }
    }
  }
}

// ---------------------------------------------------------------------------
// Kernel 3: reduce the 8 per-XCD copies -> dinv = 1/(sum + 1e-16).
// 200K threads; 8 coalesced streams in, 800KB out. ~2us.
// ---------------------------------------------------------------------------
__global__ __launch_bounds__(256) void reduce_kernel(
    const float* __restrict__ denom8, float* __restrict__ dinv, int n_nodes) {
  const int i = blockIdx.x * 256 + threadIdx.x;
  const int n4 = n_nodes * NHEAD;
  if (i >= n4) return;
  float s = 1e-16f;
#pragma unroll
  for (int xb = 0; xb < NXCD; ++xb) s += denom8[(size_t)xb * n4 + i];
  dinv[i] = 1.f / s;
}

// ---------------------------------------------------------------------------
// Kernel 4: attn[e][:] = exp(prods[e][:]) * dinv[seg][:]  (16B NT stores)
// ---------------------------------------------------------------------------
__global__ __launch_bounds__(256) void norm_kernel(
    const int* __restrict__ edge0, const float* __restrict__ dinv,
    const f32x4* __restrict__ prods4, f32x4* __restrict__ attn4, int n_edges) {
  const int e = blockIdx.x * 256 + threadIdx.x;
  if (e >= n_edges) return;
  const int seg = __builtin_nontemporal_load(&edge0[e]);
  const f32x4 p = prods4[e];
  const f32x4 iv = *(const f32x4*)&dinv[(size_t)seg * 4];
  f32x4 a;
  a.x = __expf(p.x) * iv.x;
  a.y = __expf(p.y) * iv.y;
  a.z = __expf(p.z) * iv.z;
  a.w = __expf(p.w) * iv.w;
  __builtin_nontemporal_store(a, &attn4[e]);
}

extern "C" void kernel_launch(void* const* d_in, const int* in_sizes, int n_in,
                              void* d_out, int out_size, void* d_ws, size_t ws_size,
                              hipStream_t stream) {
  const float* x  = (const float*)d_in[0];
  const int* edge = (const int*)d_in[1];
  const float* Wq = (const float*)d_in[2];
  const float* bq = (const float*)d_in[3];
  const float* Wk = (const float*)d_in[4];
  const float* bk = (const float*)d_in[5];
  const float* Wv = (const float*)d_in[6];
  const float* bv = (const float*)d_in[7];

  const int n_nodes = in_sizes[0] / 64;   // 50000
  const int n_edges = in_sizes[1] / 2;    // 1600000
  const int* edge0 = edge;
  const int* edge1 = edge + n_edges;

  // Output: attention [E*4] | v [N*64] | prods [E*4]
  float* out_attn  = (float*)d_out;
  float* out_v     = out_attn + (long long)n_edges * NHEAD;
  float* out_prods = out_v + (long long)n_nodes * 64;

  // Workspace: q bf16 [4][N][16] | k bf16 [4][N][16] | denom8 f32 [8][N*4]
  //            | dinv f32 [N*4]   (~20.8MB; 39.2MB fit verified earlier)
  bf16* ws_q = (bf16*)d_ws;
  bf16* ws_k = ws_q + (size_t)NHEAD * n_nodes * 16;
  float* ws_denom8 = (float*)(ws_k + (size_t)NHEAD * n_nodes * 16);
  float* ws_dinv = ws_denom8 + (size_t)NXCD * n_nodes * NHEAD;

  {
    const int blocks = (n_nodes + 15) / 16;  // 3125; also zeroes denom8
    qkv_kernel<<<blocks, 256, 0, stream>>>(x, Wq, bq, Wk, bk, Wv, bv,
                                           ws_q, ws_k, out_v, ws_denom8, n_nodes);
  }
  {
    const int Q = (n_edges + EPT - 1) / EPT;  // 200000
    const int blocks = (Q + 255) / 256;       // 782 -> all co-resident
    edge_kernel<<<blocks, 256, 0, stream>>>(edge0, edge1,
                                            (const uint4*)ws_q, (const uint4*)ws_k,
                                            (f32x4*)out_prods, ws_denom8,
                                            n_edges, n_nodes, Q);
  }
  {
    const int n4 = n_nodes * NHEAD;
    reduce_kernel<<<(n4 + 255) / 256, 256, 0, stream>>>(ws_denom8, ws_dinv, n_nodes);
  }
  {
    norm_kernel<<<(n_edges + 255) / 256, 256, 0, stream>>>(
        edge0, ws_dinv, (const f32x4*)out_prods, (f32x4*)out_attn, n_edges);
  }
}